// Round 1
// baseline (17315.941 us; speedup 1.0000x reference)
//
#include <hip/hip_runtime.h>
#include <stdint.h>

// B=64, L=128, H=512, LAB=128. 8192 strictly-sequential LSTM cell steps
// sharing one (h,c) of size 512:
//   gates[s] = pre[s] + W_p @ h[s-64] + W_hh @ h[s-1]
//   pre[s]   = W_ih[:, :2048] @ [x;hi] + b_ih + b_hh     (parallel GEMM)
//
// ws layout:
//   [0,32MB)        pre32: bf16-pair-packed u32 [8192][1024]
//   [32,48MB)       units: u32 [8192][512], unit = (tag16<<16)|bf16(h[j]),
//                   tag = step+1 (1..8192); 0xAA poison tag 0xAAAA never aliases.
//   [48MB,+256KB)   ring : u32 [128][512], same unit format (XCD-local path)
//   [+256KB,+4KB)   ctrl : [0]=election CAS word, [16]=rank ctr, [32]=done ctr
//
// R6: the 14ms floor of the global-scope design is the per-step MALL round
// trip (agent-scope atomics bypass the non-coherent per-XCD L2s) plus
// hot-line poll contention. New lstm_seq_xcd runs the WHOLE recurrence on
// ONE XCD elected at runtime via s_getreg(XCC_ID): 32 WGs / 128 waves, each
// wave owns 4 h-outputs; h is exchanged through a 256KB L2-resident ring
// with plain stores + sc0 (L1-bypass, L2-hit) loads => ~300cy RT instead of
// ~1300cy. All assumptions are tag-guarded: on any failure the replica
// halts silently and the proven global-scope lstm_seq (chaser, unchanged
// math) redoes the work; on success the chaser early-exits via done ctr.

#define HDIM   512
#define NSTEP  8192
#define XDIM   2048
#define IN5H   2560
#define LSEQ   128
#define LAB    128
#define SPIN_LIMIT 65536
#define NXRING 128
#define SPINX  16384

typedef float f32x4 __attribute__((ext_vector_type(4)));
typedef short bf16x8 __attribute__((ext_vector_type(8)));
typedef unsigned u32x4 __attribute__((ext_vector_type(4)));

__device__ __forceinline__ unsigned f2bf(float v){
  unsigned u = __float_as_uint(v);
  u += 0x7fffu + ((u >> 16) & 1u);      // RNE; values bounded (no NaN/Inf)
  return u >> 16;
}
__device__ __forceinline__ float bfu(unsigned half16){   // bf16 bits -> f32
  return __uint_as_float(half16 << 16);
}
template<int CTRL>
__device__ __forceinline__ float dpp_add(float x){
  const int yi = __builtin_amdgcn_update_dpp(0, __float_as_int(x), CTRL, 0xF, 0xF, true);
  return x + __int_as_float(yi);
}
// sum of x across 64 lanes, valid in lane 63 (other lanes partial)
__device__ __forceinline__ float wave_reduce63(float x){
  x = dpp_add<0x111>(x);   // row_shr:1
  x = dpp_add<0x112>(x);   // row_shr:2
  x = dpp_add<0x114>(x);   // row_shr:4
  x = dpp_add<0x118>(x);   // row_shr:8  -> lane15+16k = row sum
  x = dpp_add<0x142>(x);   // row_bcast:15
  x = dpp_add<0x143>(x);   // row_bcast:31 -> lane 63 = total
  return x;
}

// 32B lane slice load, L1-bypass / L2-visible (intra-XCD coherent).
__device__ __forceinline__ void ld32_sc0(const unsigned* p, u32x4& a, u32x4& b){
  asm volatile("global_load_dwordx4 %0, %2, off sc0\n\t"
               "global_load_dwordx4 %1, %2, off offset:16 sc0\n\t"
               "s_waitcnt vmcnt(0)"
               : "=&v"(a), "=&v"(b)
               : "v"(p)
               : "memory");
}
__device__ __forceinline__ int tagok8(u32x4 a, u32x4 b, unsigned t){
  int ok = ((a[0] >> 16) == t);
  ok &= ((a[1] >> 16) == t);
  ok &= ((a[2] >> 16) == t);
  ok &= ((a[3] >> 16) == t);
  ok &= ((b[0] >> 16) == t);
  ok &= ((b[1] >> 16) == t);
  ok &= ((b[2] >> 16) == t);
  ok &= ((b[3] >> 16) == t);
  return ok;
}
__device__ __forceinline__ void decode8(u32x4 a, u32x4 b, float* h){
  h[0] = __uint_as_float(a[0] << 16); h[1] = __uint_as_float(a[1] << 16);
  h[2] = __uint_as_float(a[2] << 16); h[3] = __uint_as_float(a[3] << 16);
  h[4] = __uint_as_float(b[0] << 16); h[5] = __uint_as_float(b[1] << 16);
  h[6] = __uint_as_float(b[2] << 16); h[7] = __uint_as_float(b[3] << 16);
}

// ---------------------------------------------------------------- phase 1
// pre[s][r] = sum_k xcat[s][k]*W_ih[r][k] + b_ih[r] + b_hh[r], bf16-packed.
__global__ __launch_bounds__(256) void gemm_pre(
    const float* __restrict__ x, const float* __restrict__ hi,
    const float* __restrict__ Wih, const float* __restrict__ bih,
    const float* __restrict__ bhh, unsigned* __restrict__ pre32)
{
  __shared__ unsigned short As[128][40];   // +8 pad, 16B-aligned b128 reads
  __shared__ unsigned short Bs[128][40];
  const int tid = threadIdx.x;
  const int bm = blockIdx.x, bn = blockIdx.y;
  const int lane = tid & 63, wv = tid >> 6;
  const int wm = wv & 1, wn = wv >> 1;

  const int srow = tid >> 1;              // staging row 0..127
  const int ch   = (tid & 1) * 16;        // col half of the 32-wide K chunk

  const int gr = bm*128 + srow;           // global s row
  const int bb = gr & 63, tt = gr >> 6;   // s = t*64 + b
  const float* ax = x  + (size_t)(bb*LSEQ + tt) * 1024;
  const float* ah = hi + (size_t)(bb*LSEQ + tt) * 1024;
  const int R = bn*128 + srow;            // global gate row
  const float* bw = Wih + (size_t)R * IN5H;

  f32x4 acc[4][4];
  #pragma unroll
  for (int m=0;m<4;++m)
    #pragma unroll
    for (int n=0;n<4;++n) acc[m][n] = (f32x4){0.f,0.f,0.f,0.f};

  for (int kc = 0; kc < XDIM; kc += 32){
    const int c0 = kc + ch;
    const float* ap = (c0 < 1024) ? (ax + c0) : (ah + (c0 - 1024));
    #pragma unroll
    for (int q=0;q<4;++q){
      float4 va = *(const float4*)(ap + 4*q);
      float4 vb = *(const float4*)(bw + c0 + 4*q);
      ushort4 ua; ua.x=f2bf(va.x); ua.y=f2bf(va.y); ua.z=f2bf(va.z); ua.w=f2bf(va.w);
      ushort4 ub; ub.x=f2bf(vb.x); ub.y=f2bf(vb.y); ub.z=f2bf(vb.z); ub.w=f2bf(vb.w);
      *(ushort4*)&As[srow][ch + 4*q] = ua;
      *(ushort4*)&Bs[srow][ch + 4*q] = ub;
    }
    __syncthreads();
    bf16x8 afr[4], bfr[4];
    const int mr = wm*64 + (lane & 15);
    const int nr = wn*64 + (lane & 15);
    const int ko = (lane >> 4) * 8;
    #pragma unroll
    for (int m=0;m<4;++m) afr[m] = *(const bf16x8*)&As[mr + 16*m][ko];
    #pragma unroll
    for (int n=0;n<4;++n) bfr[n] = *(const bf16x8*)&Bs[nr + 16*n][ko];
    #pragma unroll
    for (int m=0;m<4;++m)
      #pragma unroll
      for (int n=0;n<4;++n)
        acc[m][n] = __builtin_amdgcn_mfma_f32_16x16x32_bf16(afr[m], bfr[n], acc[m][n], 0, 0, 0);
    __syncthreads();
  }
  // C/D layout: col = lane&15 (N side), row = (lane>>4)*4+q (M side)
  #pragma unroll
  for (int n=0;n<4;++n){
    const int scol = bn*128 + wn*64 + 16*n + (lane & 15);
    const float bias = bih[scol] + bhh[scol];
    #pragma unroll
    for (int m=0;m<4;++m){
      const int sr0 = bm*128 + wm*64 + 16*m + (lane >> 4)*4;
      #pragma unroll
      for (int q=0;q<4;++q){
        const float v = acc[m][n][q] + bias;
        const float vn = __shfl_xor(v, 1, 64);     // neighbor col (scol^1)
        if (!(lane & 1)){
          const unsigned word = f2bf(v) | (f2bf(vn) << 16);
          pre32[(size_t)(sr0 + q) * 1024 + (scol >> 1)] = word;
        }
      }
    }
  }
}

// ---------------------------------------------------------------- phase 2a
// XCD-local replica. 512 WGs launched; first CAS winner's XCD is chosen;
// its 32 first-round-resident WGs (VGPR=1 WG/CU guarantees distinct CUs)
// take ranks 0..31 = 128 waves, wave wid owns h[4*wid .. 4*wid+3].
// Lane l owns columns 8l..8l+7 of h/u (matches ring lane-slice layout).
__global__ __launch_bounds__(256)
__attribute__((amdgpu_waves_per_eu(1,1)))
void lstm_seq_xcd(
    const float* __restrict__ Wih, const float* __restrict__ Whh,
    const unsigned* __restrict__ pre32, unsigned* __restrict__ units,
    unsigned* __restrict__ ring, unsigned* __restrict__ ctrl)
{
  __shared__ int sh_part;
  const int tid = threadIdx.x;
  if (tid == 0){
    // HW_REG_XCC_ID = id 20, offset 0, size 4  -> imm = 20 | (3<<11)
    const unsigned my_xcd = (unsigned)__builtin_amdgcn_s_getreg(6164) & 0xFu;
    const unsigned tagv = 0xE1EC0000u | my_xcd;
    const unsigned prev = atomicCAS(ctrl + 0, 0xAAAAAAAAu, tagv);
    const unsigned chosen = (prev == 0xAAAAAAAAu) ? tagv : prev;
    int part = -1;
    if (chosen == tagv){
      const unsigned r = atomicAdd(ctrl + 16, 1u) - 0xAAAAAAAAu;  // poison-relative rank
      if (r < 32u) part = (int)r;
    }
    sh_part = part;
  }
  __syncthreads();
  const int wgr = sh_part;
  if (wgr < 0) return;

  const int l   = tid & 63;
  const int wv  = tid >> 6;
  const int wid = wgr*4 + wv;            // 0..127
  const int j0  = wid*4;                 // my 4 outputs: j0..j0+3
  const int c0  = 8*l;                   // my 8 columns

  // ---- weights into VGPRs: [gate][m][half] of rows g*512+j0+m, cols c0.. ----
  f32x4 wh[4][4][2], wu[4][4][2];
  #pragma unroll
  for (int g=0; g<4; ++g)
    #pragma unroll
    for (int m=0; m<4; ++m){
      const float* ph = Whh + (size_t)(g*HDIM + j0 + m)*HDIM + c0;
      const float* pu = Wih + (size_t)(g*HDIM + j0 + m)*IN5H + XDIM + c0;
      wh[g][m][0] = *(const f32x4*)ph;  wh[g][m][1] = *(const f32x4*)(ph+4);
      wu[g][m][0] = *(const f32x4*)pu;  wu[g][m][1] = *(const f32x4*)(pu+4);
    }
  #pragma unroll
  for (int g=0; g<4; ++g)
    #pragma unroll
    for (int m=0; m<4; ++m){
      asm volatile("" : "+v"(wh[g][m][0]), "+v"(wh[g][m][1]));
      asm volatile("" : "+v"(wu[g][m][0]), "+v"(wu[g][m][1]));
    }

  const int pw0 = wid*2;                 // pre32 word base: rows 4wid..4wid+3
  float cst[4] = {0.f,0.f,0.f,0.f};
  int halted = 0;

  #pragma clang loop unroll(disable)
  for (int s = 0; s < NSTEP; ++s){
    // pre words (plain cached loads; latency hidden under the h poll)
    unsigned long long pwv[4];
    #pragma unroll
    for (int g=0; g<4; ++g)
      pwv[g] = __builtin_nontemporal_load(
          (const unsigned long long*)(pre32 + (size_t)s*1024 + g*256 + pw0));

    // u = h[s-64] from ring (62-step slack; blocking load is pre-poll => free)
    float uv[8];
    if (s >= 64){
      const unsigned* up = ring + (((unsigned)(s-64)) & (NXRING-1))*HDIM + c0;
      u32x4 ua, ub;
      ld32_sc0(up, ua, ub);
      const unsigned utg = (unsigned)(s - 63);
      if (!__all(tagok8(ua, ub, utg))){
        int trips = 0, ok;
        do { ld32_sc0(up, ua, ub); ok = __all(tagok8(ua, ub, utg)); }
        while (!ok && ++trips < SPINX);
        if (!ok) halted = 1;
      }
      decode8(ua, ub, uv);
    } else {
      #pragma unroll
      for (int k=0;k<8;++k) uv[k] = 0.f;
    }
    if (halted) break;

    // poll h[s-1] in ring (intra-XCD L2 round trip)
    float hv[8];
    if (s == 0){
      #pragma unroll
      for (int k=0;k<8;++k) hv[k] = 0.f;
    } else {
      const unsigned* hp = ring + (((unsigned)(s-1)) & (NXRING-1))*HDIM + c0;
      const unsigned htg = (unsigned)s;
      u32x4 ha, hb;
      int trips = 0, ok;
      do { ld32_sc0(hp, ha, hb); ok = __all(tagok8(ha, hb, htg)); }
      while (!ok && ++trips < SPINX);
      if (!ok){ halted = 1; break; }
      decode8(ha, hb, hv);
    }

    const f32x4 h40 = {hv[0],hv[1],hv[2],hv[3]}, h41 = {hv[4],hv[5],hv[6],hv[7]};
    const f32x4 u40 = {uv[0],uv[1],uv[2],uv[3]}, u41 = {uv[4],uv[5],uv[6],uv[7]};

    // 16 gate sums (float4 ops -> v_pk_fma_f32), reduced to lane 63
    float sums[4][4];
    #pragma unroll
    for (int g=0; g<4; ++g)
      #pragma unroll
      for (int m=0; m<4; ++m){
        f32x4 acc = wh[g][m][0]*h40 + wh[g][m][1]*h41
                  + wu[g][m][0]*u40 + wu[g][m][1]*u41;
        sums[g][m] = wave_reduce63(acc[0]+acc[1]+acc[2]+acc[3]);
      }

    // pointwise: 4 independent (h,c) lanes of this wave (valid in lane 63)
    unsigned pkt[4];
    const unsigned tag = (unsigned)(s + 1) << 16;
    #pragma unroll
    for (int m=0; m<4; ++m){
      float gi = sums[0][m] + bfu((unsigned)(pwv[0] >> (16*m)) & 0xffffu);
      float gf = sums[1][m] + bfu((unsigned)(pwv[1] >> (16*m)) & 0xffffu);
      float gg = sums[2][m] + bfu((unsigned)(pwv[2] >> (16*m)) & 0xffffu);
      float go = sums[3][m] + bfu((unsigned)(pwv[3] >> (16*m)) & 0xffffu);
      gi = 1.f/(1.f + __expf(-gi));
      gf = 1.f/(1.f + __expf(-gf));
      go = 1.f/(1.f + __expf(-go));
      float e2 = __expf(2.f * fminf(fmaxf(gg, -15.f), 15.f));
      gg = (e2 - 1.f) / (e2 + 1.f);
      cst[m] = gf*cst[m] + gi*gg;
      float e2c = __expf(2.f * fminf(fmaxf(cst[m], -15.f), 15.f));
      const float hval = go * ((e2c - 1.f) / (e2c + 1.f));
      pkt[m] = tag | f2bf(hval);
    }
    if (l == 63){
      u32x4 o; o[0]=pkt[0]; o[1]=pkt[1]; o[2]=pkt[2]; o[3]=pkt[3];
      *(u32x4*)(ring + (((unsigned)s) & (NXRING-1))*HDIM + j0) = o;       // L2 (drives loop)
      __builtin_nontemporal_store(o, (u32x4*)(units + (size_t)s*HDIM + j0)); // output copy
    }
  }

  if (!halted && l == 0) atomicAdd(ctrl + 32, 1u);   // per-wave completion
}

// ---------------------------------------------------------------- phase 2b
// Global-scope path (chaser / legacy). Unchanged math; early-exits when the
// XCD replica attests full completion (done == poison + 128 waves).
__global__ __launch_bounds__(256)
__attribute__((amdgpu_waves_per_eu(1,1)))
void lstm_seq(
    const float* __restrict__ Wih, const float* __restrict__ Whh,
    const unsigned* __restrict__ pre32, unsigned* __restrict__ units,
    const unsigned* __restrict__ done_ctrl)
{
  if (done_ctrl){
    if (*(volatile const unsigned*)done_ctrl == 0xAAAAAAAAu + 128u) return;
  }
  const int tid = threadIdx.x;
  const int l = tid & 63;
  const int j0 = blockIdx.x * 4 + (tid >> 6);      // 0..511

  // ---- weights into VGPRs (once): col(k) = 2l + 128*(k>>1) + (k&1) ----
  float wh[4][8], wu[4][8];
  #pragma unroll
  for (int g=0; g<4; ++g){
    const float* ph = Whh + (size_t)(g*HDIM + j0)*HDIM;
    const float* pu = Wih + (size_t)(g*HDIM + j0)*IN5H + XDIM;
    #pragma unroll
    for (int k=0; k<8; ++k){
      const int col = 2*l + 128*(k>>1) + (k&1);
      wh[g][k] = ph[col]; wu[g][k] = pu[col];
    }
  }
  #pragma unroll
  for (int g=0; g<4; ++g)
    #pragma unroll
    for (int k=0; k<8; ++k){
      asm volatile("" : "+v"(wh[g][k]));
      asm volatile("" : "+v"(wu[g][k]));
    }

  const int phalf = j0 >> 1, psel = j0 & 1;
  float pr[4];
  #pragma unroll
  for (int g=0; g<4; ++g){
    const unsigned w0 = pre32[(size_t)0*1024 + g*256 + phalf];
    pr[g] = psel ? bfu(w0 >> 16) : bfu(w0 & 0xffffu);
  }

  float uvc[8];
  #pragma unroll
  for (int k=0;k<8;++k) uvc[k] = 0.f;

  float cst = 0.f;
  int dead = 0;

  for (int s = 0; s < NSTEP; ++s){
    unsigned pw[4];
    const bool pf  = (s + 1 < NSTEP);
    const bool upf = (s + 1 >= 64) && pf;
    if (pf){
      #pragma unroll
      for (int g=0; g<4; ++g)
        pw[g] = pre32[(size_t)(s+1)*1024 + g*256 + phalf];
    }
    unsigned long long un[4];
    if (upf){
      const unsigned long long* bp =
          (const unsigned long long*)(units + (size_t)(s-63)*HDIM) + l;
      #pragma unroll
      for (int c=0;c<4;++c)
        un[c] = __hip_atomic_load(bp + 64*c, __ATOMIC_RELAXED, __HIP_MEMORY_SCOPE_AGENT);
    }

    float hv[8];
    if (s == 0){
      #pragma unroll
      for (int k=0;k<8;++k) hv[k] = 0.f;
    } else {
      const unsigned long long* bp =
          (const unsigned long long*)(units + (size_t)(s-1)*HDIM) + l;
      unsigned long long v[4];
      if (dead){
        #pragma unroll
        for (int c=0;c<4;++c) v[c] = __hip_atomic_load(bp + 64*c, __ATOMIC_RELAXED, __HIP_MEMORY_SCOPE_AGENT);
      } else {
        int trips = 0, ok;
        do {
          #pragma unroll
          for (int c=0;c<4;++c) v[c] = __hip_atomic_load(bp + 64*c, __ATOMIC_RELAXED, __HIP_MEMORY_SCOPE_AGENT);
          int lok = 1;
          #pragma unroll
          for (int c=0;c<4;++c){
            lok &= (((unsigned)(v[c] >> 16) & 0xffffu) == (unsigned)s);
            lok &= (((unsigned)(v[c] >> 48)) == (unsigned)s);
          }
          ok = __all(lok);
        } while (!ok && ++trips < SPIN_LIMIT);
        if (!ok) dead = 1;
      }
      #pragma unroll
      for (int c=0;c<4;++c){
        hv[2*c]   = bfu((unsigned)v[c] & 0xffffu);
        hv[2*c+1] = bfu((unsigned)(v[c] >> 32) & 0xffffu);
      }
    }

    float a0=0.f, a1=0.f, a2=0.f, a3=0.f;
    #pragma unroll
    for (int k=0;k<8;++k){
      a0 += wh[0][k]*hv[k]; a1 += wh[1][k]*hv[k];
      a2 += wh[2][k]*hv[k]; a3 += wh[3][k]*hv[k];
    }
    #pragma unroll
    for (int k=0;k<8;++k){
      a0 += wu[0][k]*uvc[k]; a1 += wu[1][k]*uvc[k];
      a2 += wu[2][k]*uvc[k]; a3 += wu[3][k]*uvc[k];
    }
    a0 = wave_reduce63(a0);
    a1 = wave_reduce63(a1);
    a2 = wave_reduce63(a2);
    a3 = wave_reduce63(a3);

    float gi = a0 + pr[0];
    float gf = a1 + pr[1];
    float gg = a2 + pr[2];
    float go = a3 + pr[3];
    gi = 1.f/(1.f + __expf(-gi));
    gf = 1.f/(1.f + __expf(-gf));
    go = 1.f/(1.f + __expf(-go));
    float e2 = __expf(2.f * fminf(fmaxf(gg, -15.f), 15.f));
    gg = (e2 - 1.f) / (e2 + 1.f);
    cst = gf*cst + gi*gg;
    float e2c = __expf(2.f * fminf(fmaxf(cst, -15.f), 15.f));
    const float hval = go * ((e2c - 1.f) / (e2c + 1.f));

    if (l == 63){
      const unsigned unit = ((unsigned)(s + 1) << 16) | f2bf(hval);
      __hip_atomic_store(units + (size_t)s*HDIM + j0, unit,
                         __ATOMIC_RELAXED, __HIP_MEMORY_SCOPE_AGENT);
    }

    if (upf){
      int lok = 1;
      #pragma unroll
      for (int c=0;c<4;++c){
        lok &= (((unsigned)(un[c] >> 16) & 0xffffu) == (unsigned)(s-62));
        lok &= (((unsigned)(un[c] >> 48)) == (unsigned)(s-62));
      }
      if (!__all(lok) && !dead){
        const unsigned long long* bp =
            (const unsigned long long*)(units + (size_t)(s-63)*HDIM) + l;
        int trips = 0, ok;
        do {
          #pragma unroll
          for (int c=0;c<4;++c)
            un[c] = __hip_atomic_load(bp + 64*c, __ATOMIC_RELAXED, __HIP_MEMORY_SCOPE_AGENT);
          int lk = 1;
          #pragma unroll
          for (int c=0;c<4;++c){
            lk &= (((unsigned)(un[c] >> 16) & 0xffffu) == (unsigned)(s-62));
            lk &= (((unsigned)(un[c] >> 48)) == (unsigned)(s-62));
          }
          ok = __all(lk);
        } while (!ok && ++trips < SPIN_LIMIT);
        if (!ok) dead = 1;
      }
      #pragma unroll
      for (int c=0;c<4;++c){
        uvc[2*c]   = bfu((unsigned)un[c] & 0xffffu);
        uvc[2*c+1] = bfu((unsigned)(un[c] >> 32) & 0xffffu);
      }
    } else {
      #pragma unroll
      for (int k=0;k<8;++k) uvc[k] = 0.f;
    }
    if (pf){
      #pragma unroll
      for (int g=0; g<4; ++g)
        pr[g] = psel ? bfu(pw[g] >> 16) : bfu(pw[g] & 0xffffu);
    }
  }
}

// ---------------------------------------------------------------- phase 3
// y[b][t][lab] = sum_j h[s][j] * W_fc[lab][j] + b_fc[lab],  s = t*64 + b
__global__ __launch_bounds__(256) void fc_kernel(
    const unsigned* __restrict__ units,
    const float* __restrict__ Wfc, const float* __restrict__ bfc,
    float* __restrict__ out)
{
  __shared__ float hbuf[8][512];
  const int tid = threadIdx.x;
  const int s0 = blockIdx.x * 8;
  #pragma unroll
  for (int r=0;r<16;++r){
    const int q = tid + 256*r;                 // 0..4095
    const int si = q >> 9, j = q & 511;
    hbuf[si][j] = bfu(units[(size_t)(s0 + si)*HDIM + j] & 0xffffu);
  }
  __syncthreads();
  const int lab = tid & 127, sg = tid >> 7;
  const float* wrow = Wfc + (size_t)lab * HDIM;
  const float bias = bfc[lab];
  for (int si = sg; si < 8; si += 2){
    float sum = 0.f;
    #pragma unroll 4
    for (int j=0;j<HDIM;j+=4){
      const float4 wv = *(const float4*)(wrow + j);
      sum += wv.x*hbuf[si][j] + wv.y*hbuf[si][j+1]
           + wv.z*hbuf[si][j+2] + wv.w*hbuf[si][j+3];
    }
    const int s = s0 + si;
    const int bb = s & 63, tt = s >> 6;
    out[((size_t)(bb*LSEQ + tt))*LAB + lab] = sum + bias;
  }
}

__global__ void sentinel_kernel(float* out, int n){
  const int i = blockIdx.x*256 + threadIdx.x;
  if (i < n) out[i] = 12345.0f;     // diagnostic: ws_size too small
}

extern "C" void kernel_launch(void* const* d_in, const int* in_sizes, int n_in,
                              void* d_out, int out_size, void* d_ws, size_t ws_size,
                              hipStream_t stream)
{
  const float* x   = (const float*)d_in[0];
  const float* hi  = (const float*)d_in[1];
  const float* Wih = (const float*)d_in[2];
  const float* Whh = (const float*)d_in[3];
  const float* bih = (const float*)d_in[4];
  const float* bhh = (const float*)d_in[5];
  const float* Wfc = (const float*)d_in[6];
  const float* bfc = (const float*)d_in[7];
  float* out = (float*)d_out;

  const size_t MB = 1024*1024;
  if (ws_size >= 49*MB){
    unsigned* pre32 = (unsigned*)d_ws;                               // 32MB
    unsigned* units = (unsigned*)((char*)d_ws + 32*MB);              // 16MB
    unsigned* ring  = (unsigned*)((char*)d_ws + 48*MB);              // 256KB
    unsigned* ctrl  = (unsigned*)((char*)d_ws + 48*MB + 256*1024);   // 4KB
    gemm_pre<<<dim3(64, 16), 256, 0, stream>>>(x, hi, Wih, bih, bhh, pre32);
    lstm_seq_xcd<<<512, 256, 0, stream>>>(Wih, Whh, pre32, units, ring, ctrl);
    lstm_seq<<<128, 256, 0, stream>>>(Wih, Whh, pre32, units, ctrl + 32);
    fc_kernel<<<1024, 256, 0, stream>>>(units, Wfc, bfc, out);
  } else if (ws_size >= 48*MB){
    unsigned* pre32 = (unsigned*)d_ws;                               // 32MB
    unsigned* units = (unsigned*)((char*)d_ws + 32*MB);              // 16MB
    gemm_pre<<<dim3(64, 16), 256, 0, stream>>>(x, hi, Wih, bih, bhh, pre32);
    lstm_seq<<<128, 256, 0, stream>>>(Wih, Whh, pre32, units, nullptr);
    fc_kernel<<<1024, 256, 0, stream>>>(units, Wfc, bfc, out);
  } else {
    sentinel_kernel<<<(out_size + 255)/256, 256, 0, stream>>>(out, out_size);
  }
}